// Round 3
// baseline (767.846 us; speedup 1.0000x reference)
//
#include <hip/hip_runtime.h>

typedef unsigned int u32;
typedef unsigned short u16;
typedef __attribute__((ext_vector_type(8))) short short8;   // 8 bf16 (4 VGPRs)
typedef __attribute__((ext_vector_type(4))) float f32x4;
typedef __attribute__((ext_vector_type(2))) float f32x2;

#define DEV __device__ __forceinline__
#define LOG2E 1.44269504089f

DEV u16 f2bf(float f) {
    u32 u = __float_as_uint(f);
    return (u16)((u + 0x7FFFu + ((u >> 16) & 1u)) >> 16);
}
DEV float bf2f(u16 h) { return __uint_as_float(((u32)h) << 16); }
DEV float frcp(float x) { return __builtin_amdgcn_rcpf(x); }
DEV float fexp2(float x) {
#if __has_builtin(__builtin_amdgcn_exp2f)
    return __builtin_amdgcn_exp2f(x);
#else
    return exp2f(x);
#endif
}
DEV u32 pack_bf16(float a, float b) {
#if __has_builtin(__builtin_amdgcn_cvt_pk_bf16_f32)
    auto v = __builtin_amdgcn_cvt_pk_bf16_f32(a, b);   // lo=a, hi=b
    u32 r; __builtin_memcpy(&r, &v, 4); return r;
#else
    return (u32)f2bf(a) | ((u32)f2bf(b) << 16);
#endif
}
// extract r-th bf16 (r constant under unroll) from packed uint2
DEV float xex(uint2 v, int r) {
    u32 u = (r & 2) ? v.y : v.x;
    return (r & 1) ? __uint_as_float(u & 0xFFFF0000u) : __uint_as_float(u << 16);
}

// gate permutation: NEW gate id g = ch*4 + type  ->  OLD row = type*128 + ch.
// Makes each 16-gate M-tile hold 4 channels x 4 types, so each thread's 4
// C-frag elements of one tile are {zi,zf,zg,zo} of ONE channel (nonlin can
// start after 4 MFMAs instead of 16 -> MFMA/trans phase overlap).
DEV int gmap(int g) { return (g & 3) * 128 + (g >> 2); }

// packed-pair helpers (numerics identical to scalar; pk ops where they exist)
DEV f32x2 exp2p(f32x2 a) { f32x2 r; r.x = fexp2(a.x); r.y = fexp2(a.y); return r; }
DEV f32x2 rcpp(f32x2 a)  { f32x2 r; r.x = frcp(a.x);  r.y = frcp(a.y);  return r; }
DEV f32x2 minp(f32x2 a, float b) { f32x2 r; r.x = fminf(a.x, b); r.y = fminf(a.y, b); return r; }

// one LSTM elementwise step on a PAIR of channels (same expressions / op order
// as the proven scalar version)
DEV f32x2 lstm_pair(f32x2 zi, f32x2 zf, f32x2 zg, f32x2 zo, f32x2* cst) {
    f32x2 ei = exp2p(-zi);
    f32x2 ef = exp2p(-zf);
    f32x2 eo = exp2p(-zo);
    f32x2 eg = exp2p(minp(zg + zg, 115.f));
    f32x2 A = 1.f + ei, F = 1.f + ef, G = eg + 1.f, O = 1.f + eo;
    f32x2 AG = A * G;
    f32x2 cc = (*cst * AG + (eg - 1.f) * F) * rcpp(F * AG);
    *cst = cc;
    f32x2 ec = exp2p(minp(cc * 2.885390082f, 115.f));
    return (ec - 1.f) * rcpp(O * (ec + 1.f));
}

// ---------------------------------------------------------------------------
// K1: fused embedding gather + input projection, MFMA, both dirs.
// 256 blocks = 2 dirs x 128 chunks of 4 s-steps.  X layout = C-frag-swizzled
// in the NEW (gate-interleaved) row order; pre-scaled by log2e.
// ---------------------------------------------------------------------------
__global__ __launch_bounds__(512) void k_inproj2(
    const int* __restrict__ sent, const float* __restrict__ emb,
    const float* __restrict__ wihf, const float* __restrict__ bihf, const float* __restrict__ bhhf,
    const float* __restrict__ wihb, const float* __restrict__ bihb, const float* __restrict__ bhhb,
    u16* __restrict__ Xf, u16* __restrict__ Xb)
{
    int blk = blockIdx.x;
    int d  = blk >> 7;
    int sc = blk & 127;                    // 4 s-steps per block
    const float* wih = d ? wihb : wihf;
    const float* bih = d ? bihb : bihf;
    const float* bhh = d ? bhhb : bhhf;
    u16* X = d ? Xb : Xf;
    int tid = threadIdx.x;
    int w = tid >> 6, lane = tid & 63;
    int rg = lane >> 4, cn = lane & 15;

    short8 afr[4][4];                      // A[m=lane&15][k=(lane>>4)*8+j]
    #pragma unroll
    for (int mi = 0; mi < 4; ++mi) {
        int gate = gmap(16 * (w + 8 * mi) + cn);   // permuted row
        #pragma unroll
        for (int kt = 0; kt < 4; ++kt) {
            const float* p = wih + (size_t)gate * 128 + kt * 32 + rg * 8;
            float4 f0 = *(const float4*)p;
            float4 f1 = *(const float4*)(p + 4);
            union { short8 v; u32 u[4]; } sv;
            sv.u[0] = pack_bf16(f0.x, f0.y);
            sv.u[1] = pack_bf16(f0.z, f0.w);
            sv.u[2] = pack_bf16(f1.x, f1.y);
            sv.u[3] = pack_bf16(f1.z, f1.w);
            afr[mi][kt] = sv.v;
        }
    }
    float bs[4][4];
    #pragma unroll
    for (int mi = 0; mi < 4; ++mi)
        #pragma unroll
        for (int r = 0; r < 4; ++r) {
            int g = gmap(16 * (w + 8 * mi) + 4 * rg + r);
            bs[mi][r] = bih[g] + bhh[g];
        }

    __shared__ u16 tile[2][64][136];       // 2 s-steps x 64 batch x 128 ch
    #pragma unroll
    for (int stage = 0; stage < 2; ++stage) {
        if (stage) __syncthreads();        // protect LDS reuse
        {
            int row = tid >> 2, q = tid & 3;   // 128 rows (2s x 64b), 32 ch each
            int sl = row >> 6, bb = row & 63;
            int tok = sent[(sc * 4 + stage * 2 + sl) * 64 + bb];
            const float* er = emb + (size_t)tok * 128 + q * 32;
            u16* dst = &tile[sl][bb][q * 32];
            #pragma unroll
            for (int u = 0; u < 4; ++u) {
                float4 a = *(const float4*)(er + u * 8);
                float4 c = *(const float4*)(er + u * 8 + 4);
                uint4 st;
                st.x = pack_bf16(a.x, a.y); st.y = pack_bf16(a.z, a.w);
                st.z = pack_bf16(c.x, c.y); st.w = pack_bf16(c.z, c.w);
                *(uint4*)(dst + u * 8) = st;
            }
        }
        __syncthreads();
        #pragma unroll
        for (int ss = 0; ss < 2; ++ss) {
            int s = sc * 4 + stage * 2 + ss;
            #pragma unroll
            for (int nt = 0; nt < 4; ++nt) {       // N-tile = batch group g4
                short8 bfr[4];
                #pragma unroll
                for (int kt = 0; kt < 4; ++kt)
                    bfr[kt] = *(const short8*)&tile[ss][nt * 16 + cn][kt * 32 + rg * 8];
                #pragma unroll
                for (int mi = 0; mi < 4; ++mi) {
                    f32x4 acc = {0.f, 0.f, 0.f, 0.f};
                    #pragma unroll
                    for (int kt = 0; kt < 4; ++kt)
                        acc = __builtin_amdgcn_mfma_f32_16x16x32_bf16(afr[mi][kt], bfr[kt], acc, 0, 0, 0);
                    size_t base = (((size_t)s * 4 + nt) * 32 + (w + 8 * mi)) * 256
                                + (size_t)rg * 64 + (size_t)cn * 4;
                    uint2 st;
                    st.x = pack_bf16((acc[0] + bs[mi][0]) * LOG2E, (acc[1] + bs[mi][1]) * LOG2E);
                    st.y = pack_bf16((acc[2] + bs[mi][2]) * LOG2E, (acc[3] + bs[mi][3]) * LOG2E);
                    *(uint2*)(X + base) = st;
                }
            }
        }
    }
}

// ---------------------------------------------------------------------------
// K2 (R11): 8-wave structure + gate-interleaved tiles.  Each thread's tile mi
// yields {zi,zf,zg,zo} of channel ch_mi = 4*(w+8*mi)+rg, so nonlin for tile 0
// overlaps the MFMAs of tiles 1-3 (breaks the MFMA->nonlin phase barrier).
// h writes become 4 scattered u16 (lo/hi halves of two packed pairs).
// ---------------------------------------------------------------------------
__global__ __launch_bounds__(512) void k_lstm(
    const float* __restrict__ h0, const float* __restrict__ c0,
    const float* __restrict__ whhf, const float* __restrict__ whhb,
    const u16* __restrict__ Xf, const u16* __restrict__ Xb,
    u16* __restrict__ hfo, u16* __restrict__ hbo)
{
    int d  = blockIdx.x >> 2, g4 = blockIdx.x & 3;
    const float* whh = d ? whhb : whhf;
    const u16*   X   = d ? Xb   : Xf;
    u16*         ho  = d ? hbo  : hfo;
    int w = threadIdx.x >> 6, lane = threadIdx.x & 63;
    int rg = lane >> 4, cn = lane & 15;

    short8 afr[4][4];                  // whh * log2e, A-frag layout (permuted rows)
    #pragma unroll
    for (int mi = 0; mi < 4; ++mi) {
        int gate = gmap(16 * (w + 8 * mi) + cn);
        #pragma unroll
        for (int kt = 0; kt < 4; ++kt) {
            const float* p = whh + (size_t)gate * 128 + kt * 32 + rg * 8;
            float4 f0 = *(const float4*)p;
            float4 f1 = *(const float4*)(p + 4);
            union { short8 v; u32 u[4]; } sv;
            sv.u[0] = pack_bf16(f0.x * LOG2E, f0.y * LOG2E);
            sv.u[1] = pack_bf16(f0.z * LOG2E, f0.w * LOG2E);
            sv.u[2] = pack_bf16(f1.x * LOG2E, f1.y * LOG2E);
            sv.u[3] = pack_bf16(f1.z * LOG2E, f1.w * LOG2E);
            afr[mi][kt] = sv.v;
        }
    }
    int b = g4 * 16 + cn;
    int ch0 = 4 * w + rg;              // channel of tile mi is ch0 + 32*mi
    f32x2 cstA, cstB;
    {
        const float* cp = c0 + ((size_t)d * 64 + b) * 128 + ch0;
        cstA.x = cp[0]; cstA.y = cp[32]; cstB.x = cp[64]; cstB.y = cp[96];
    }
    __shared__ u16 hbuf[2][16][136];
    {
        int chb = 16 * w + rg * 4;     // init coverage uses the old quad split
        float4 hv = *(const float4*)(h0 + ((size_t)d * 64 + b) * 128 + chb);
        uint2 st0;
        st0.x = pack_bf16(hv.x, hv.y);
        st0.y = pack_bf16(hv.z, hv.w);
        *(uint2*)&hbuf[0][cn][chb] = st0;
    }
    __syncthreads();

    int s0 = d ? 511 : 0;
    const int sdelta = d ? -32768 : 32768;      // X u16 elems per s-step
    const ptrdiff_t hdelta = d ? -8192 : 8192;  // 64*128 u16 per s-step
    size_t lof = (size_t)rg * 64 + (size_t)cn * 4;

    const u16* pa[4]; const u16* pb[4];
    uint2 xA[4], xB[4];
    #pragma unroll
    for (int mi = 0; mi < 4; ++mi) {
        const u16* base = X + (((size_t)s0 * 4 + g4) * 32 + (w + 8 * mi)) * 256 + lof;
        xA[mi] = *(const uint2*)base;
        xB[mi] = *(const uint2*)(base + sdelta);
        pa[mi] = base + 2 * sdelta;
        pb[mi] = base + 3 * sdelta;
    }
    u16* hop = ho + ((size_t)s0 * 64 + b) * 128 + ch0;

#define LSTM_STEP(RB, WB, XC, XP)                                            \
    do {                                                                     \
        short8 bfr[4];                                                       \
        _Pragma("unroll")                                                    \
        for (int kt = 0; kt < 4; ++kt)                                       \
            bfr[kt] = *(const short8*)&hbuf[RB][cn][kt * 32 + rg * 8];       \
        f32x4 z[4];                                                          \
        _Pragma("unroll")                                                    \
        for (int mi = 0; mi < 4; ++mi) {                                     \
            f32x4 acc;                                                       \
            acc[0] = xex(XC[mi], 0); acc[1] = xex(XC[mi], 1);                \
            acc[2] = xex(XC[mi], 2); acc[3] = xex(XC[mi], 3);                \
            _Pragma("unroll")                                                \
            for (int kt = 0; kt < 4; ++kt)                                   \
                acc = __builtin_amdgcn_mfma_f32_16x16x32_bf16(               \
                    afr[mi][kt], bfr[kt], acc, 0, 0, 0);                     \
            z[mi] = acc;                                                     \
            XC[mi] = *(const uint2*)XP[mi];                                  \
            XP[mi] += 2 * sdelta;                                            \
        }                                                                    \
        f32x2 ziA = {z[0][0], z[1][0]}, zfA = {z[0][1], z[1][1]};            \
        f32x2 zgA = {z[0][2], z[1][2]}, zoA = {z[0][3], z[1][3]};            \
        f32x2 hA = lstm_pair(ziA, zfA, zgA, zoA, &cstA);                     \
        f32x2 ziB = {z[2][0], z[3][0]}, zfB = {z[2][1], z[3][1]};            \
        f32x2 zgB = {z[2][2], z[3][2]}, zoB = {z[2][3], z[3][3]};            \
        f32x2 hB = lstm_pair(ziB, zfB, zgB, zoB, &cstB);                     \
        u32 pAw = pack_bf16(hA.x, hA.y);                                     \
        u32 pBw = pack_bf16(hB.x, hB.y);                                     \
        u16* hb = &hbuf[WB][cn][ch0];                                        \
        hb[0]  = (u16)pAw; hb[32] = (u16)(pAw >> 16);                        \
        hb[64] = (u16)pBw; hb[96] = (u16)(pBw >> 16);                        \
        hop[0]  = (u16)pAw; hop[32] = (u16)(pAw >> 16);                      \
        hop[64] = (u16)pBw; hop[96] = (u16)(pBw >> 16);                      \
        hop += hdelta;                                                       \
        asm volatile("s_waitcnt lgkmcnt(0)\n\ts_barrier" ::: "memory");      \
    } while (0)

    for (int it = 0; it < 256; ++it) {
        LSTM_STEP(0, 1, xA, pa);
        LSTM_STEP(1, 0, xB, pb);
    }
#undef LSTM_STEP
}

// ---------------------------------------------------------------------------
// K3: feats[s,b,t] = [hf|hb] . w_out[t] + b_out[t].   block handles 32 pos.
// R11: paired reads (u32 for bf16 pairs, float2 for weights) halve LDS insts.
// ---------------------------------------------------------------------------
__global__ __launch_bounds__(256) void k_feats(
    const u16* __restrict__ hf, const u16* __restrict__ hb,
    const float* __restrict__ wout, const float* __restrict__ bout,
    float* __restrict__ feats)
{
    __shared__ u16 sf[32][136], sb[32][136];
    __shared__ float wo[7][260];
    __shared__ float bo[8];
    int tid = threadIdx.x;
    int pos0 = blockIdx.x * 32;
    {
        int r = tid >> 3, cc = (tid & 7) * 16;
        const uint4* pf = (const uint4*)(hf + (size_t)(pos0 + r) * 128 + cc);
        const uint4* pb = (const uint4*)(hb + (size_t)(pos0 + r) * 128 + cc);
        *(uint4*)&sf[r][cc]     = pf[0];
        *(uint4*)&sf[r][cc + 8] = pf[1];
        *(uint4*)&sb[r][cc]     = pb[0];
        *(uint4*)&sb[r][cc + 8] = pb[1];
    }
    for (int i = tid; i < 1792; i += 256) wo[i >> 8][i & 255] = wout[i];
    if (tid < 7) bo[tid] = bout[tid];
    __syncthreads();
    int pp = tid >> 3, tt = tid & 7;
    if (tt < 7) {
        float acc = bo[tt];
        #pragma unroll 4
        for (int ch = 0; ch < 128; ch += 2) {
            u32 uf = *(const u32*)&sf[pp][ch];
            u32 ub = *(const u32*)&sb[pp][ch];
            float2 w0 = *(const float2*)&wo[tt][ch];
            float2 w1 = *(const float2*)&wo[tt][128 + ch];
            acc += __uint_as_float(uf << 16) * w0.x
                 + __uint_as_float(uf & 0xFFFF0000u) * w0.y
                 + __uint_as_float(ub << 16) * w1.x
                 + __uint_as_float(ub & 0xFFFF0000u) * w1.y;
        }
        feats[(size_t)(pos0 + pp) * 7 + tt] = acc;
    }
}

// ---------------------------------------------------------------------------
// K4a: CRF chunk fold.  block=(b, chunk of 64 steps).  512 blocks.
// ---------------------------------------------------------------------------
__global__ __launch_bounds__(64) void k_crf_chunk(
    const float* __restrict__ feats, const float* __restrict__ trans,
    float* __restrict__ chunkM)
{
    int b = blockIdx.x >> 3, c = blockIdx.x & 7;
    int lane = threadIdx.x;
    int i = lane >> 3, j = lane & 7;
    __shared__ float M[8][8];
    __shared__ float fl[64][8];
    int s0 = c * 64;
    for (int idx = lane; idx < 448; idx += 64) {
        int ss = idx / 7, jj = idx - ss * 7;
        fl[ss][jj] = feats[(size_t)((s0 + ss) * 64 + b) * 7 + jj];
    }
    float tc[7];
    #pragma unroll
    for (int k = 0; k < 7; ++k) tc[k] = (j < 7) ? trans[k * 7 + j] : 0.f;
    __syncthreads();
    M[i][j] = (i < 7 && j < 7) ? (trans[i * 7 + j] + fl[0][j]) : -1e30f;
    __syncthreads();
    for (int ss = 1; ss < 64; ++ss) {
        float4 m0 = *(const float4*)&M[i][0];
        float4 m1 = *(const float4*)&M[i][4];
        float v0 = m0.x + tc[0], v1 = m0.y + tc[1], v2 = m0.z + tc[2];
        float v3 = m0.w + tc[3], v4 = m1.x + tc[4], v5 = m1.y + tc[5];
        float v6 = m1.z + tc[6];
        float mx = fmaxf(fmaxf(fmaxf(v0, v1), fmaxf(v2, v3)),
                         fmaxf(fmaxf(v4, v5), v6));
        float sm = __expf(v0 - mx) + __expf(v1 - mx) + __expf(v2 - mx)
                 + __expf(v3 - mx) + __expf(v4 - mx) + __expf(v5 - mx)
                 + __expf(v6 - mx);
        float r = mx + __logf(sm) + fl[ss][j];
        __syncthreads();
        if (i < 7 && j < 7) M[i][j] = r;
        __syncthreads();
    }
    if (i < 7 && j < 7)
        chunkM[(size_t)(b * 8 + c) * 49 + i * 7 + j] = M[i][j];
}

// ---------------------------------------------------------------------------
// K4b: SINGLE-block final fold.  8 waves x 8 batches; lane = k*8+j
// handles (batch w*8+k, tag j).  Folds 8 chunk matrices via shuffle-lse,
// adds STOP row, computes gold with all 512 threads, block-reduces, and
// writes d_out[0] with a plain store (no memset node, no atomic).
// ---------------------------------------------------------------------------
__global__ __launch_bounds__(512) void k_crf_final(
    const float* __restrict__ chunkM, const float* __restrict__ trans,
    const int* __restrict__ tags, const float* __restrict__ feats,
    float* __restrict__ out)
{
    int tid = threadIdx.x;
    int w = tid >> 6, lane = tid & 63;
    int k = lane >> 3, j = lane & 7;
    int b = w * 8 + k;
    bool jv = (j < 7);
    __shared__ float Tl[49];
    __shared__ float red[512];
    __shared__ float fsh[64];
    if (tid < 49) Tl[tid] = trans[tid];
    __syncthreads();

    float av = (j == 5) ? 0.f : -1e4f;          // alpha0
    #pragma unroll
    for (int c = 0; c < 8; ++c) {
        float a0 = __shfl(av, k * 8 + 0, 64);
        float a1 = __shfl(av, k * 8 + 1, 64);
        float a2 = __shfl(av, k * 8 + 2, 64);
        float a3 = __shfl(av, k * 8 + 3, 64);
        float a4 = __shfl(av, k * 8 + 4, 64);
        float a5 = __shfl(av, k * 8 + 5, 64);
        float a6 = __shfl(av, k * 8 + 6, 64);
        if (jv) {
            const float* Pp = chunkM + ((size_t)b * 8 + c) * 49 + j;
            float v0 = a0 + Pp[0],  v1 = a1 + Pp[7],  v2 = a2 + Pp[14];
            float v3 = a3 + Pp[21], v4 = a4 + Pp[28], v5 = a5 + Pp[35];
            float v6 = a6 + Pp[42];
            float mx = fmaxf(fmaxf(fmaxf(v0, v1), fmaxf(v2, v3)),
                             fmaxf(fmaxf(v4, v5), v6));
            float sm = __expf(v0 - mx) + __expf(v1 - mx) + __expf(v2 - mx)
                     + __expf(v3 - mx) + __expf(v4 - mx) + __expf(v5 - mx)
                     + __expf(v6 - mx);
            av = mx + __logf(sm);
        }
    }
    // fwd = lse_j(av[j] + trans[STOP=6][j]) over the 8-lane j-group
    float u = jv ? (av + Tl[42 + j]) : -1e30f;
    float m = u;
    #pragma unroll
    for (int off = 1; off < 8; off <<= 1) m = fmaxf(m, __shfl_xor(m, off, 64));
    float e = jv ? __expf(u - m) : 0.f;
    #pragma unroll
    for (int off = 1; off < 8; off <<= 1) e += __shfl_xor(e, off, 64);
    float fwd = m + __logf(e);
    if (j == 0) fsh[b] = fwd;

    // gold: thread handles batch tb, quarter q (64 steps each)
    int tb = tid & 63, q = tid >> 6;
    const int* tgp = tags + (size_t)tb * 512;
    float acc = 0.f;
    int tp = (q == 0) ? 5 : tgp[q * 64 - 1];
    for (int ss = q * 64; ss < q * 64 + 64; ++ss) {
        int tn = tgp[ss];
        acc += Tl[tn * 7 + tp] + feats[(size_t)(ss * 64 + tb) * 7 + tn];
        tp = tn;
    }
    if (q == 7) acc += Tl[42 + tgp[511]];
    red[tid] = acc;
    __syncthreads();
    if (tid < 64) {
        float g = red[tid];
        #pragma unroll
        for (int qq = 1; qq < 8; ++qq) g += red[tid + 64 * qq];
        red[tid] = fsh[tid] - g;
    }
    __syncthreads();
    if (tid < 64) {
        float v = red[tid];
        #pragma unroll
        for (int off = 1; off < 64; off <<= 1) v += __shfl_xor(v, off, 64);
        if (tid == 0) out[0] = v * (1.0f / 64.0f);
    }
}

// ---------------------------------------------------------------------------
extern "C" void kernel_launch(void* const* d_in, const int* in_sizes, int n_in,
                              void* d_out, int out_size, void* d_ws, size_t ws_size,
                              hipStream_t stream) {
    const int*   sent = (const int*)d_in[0];
    const int*   tags = (const int*)d_in[1];
    const float* h0   = (const float*)d_in[2];
    const float* c0   = (const float*)d_in[3];
    const float* emb  = (const float*)d_in[4];
    const float* wihf = (const float*)d_in[5];
    const float* whhf = (const float*)d_in[6];
    const float* bihf = (const float*)d_in[7];
    const float* bhhf = (const float*)d_in[8];
    const float* wihb = (const float*)d_in[9];
    const float* whhb = (const float*)d_in[10];
    const float* bihb = (const float*)d_in[11];
    const float* bhhb = (const float*)d_in[12];
    const float* wout = (const float*)d_in[13];
    const float* bout = (const float*)d_in[14];
    const float* trn  = (const float*)d_in[15];

    char* ws = (char*)d_ws;
    u16*   Xf     = (u16*)(ws);                       // 33,554,432 B
    u16*   Xb     = (u16*)(ws + 33554432);            // 33,554,432 B
    u16*   hfp    = (u16*)(ws + 67108864);            //  8,388,608 B
    u16*   hbp    = (u16*)(ws + 75497472);            //  8,388,608 B
    float* feats  = (float*)(ws + 83886080);          //    917,504 B
    float* chunkM = (float*)(ws + 84803584);          //    100,352 B

    k_inproj2<<<256, 512, 0, stream>>>(sent, emb, wihf, bihf, bhhf,
                                       wihb, bihb, bhhb, Xf, Xb);
    k_lstm<<<8, 512, 0, stream>>>(h0, c0, whhf, whhb, Xf, Xb, hfp, hbp);
    k_feats<<<1024, 256, 0, stream>>>(hfp, hbp, wout, bout, feats);
    k_crf_chunk<<<512, 64, 0, stream>>>(feats, trn, chunkM);
    k_crf_final<<<1, 512, 0, stream>>>(chunkM, trn, tags, feats, (float*)d_out);
}

// Round 4
// 627.578 us; speedup vs baseline: 1.2235x; 1.2235x over previous
//
#include <hip/hip_runtime.h>

typedef unsigned int u32;
typedef unsigned short u16;
typedef __attribute__((ext_vector_type(8))) short short8;   // 8 bf16 (4 VGPRs)
typedef __attribute__((ext_vector_type(4))) float f32x4;
typedef __attribute__((ext_vector_type(2))) float f32x2;

#define DEV __device__ __forceinline__
#define LOG2E 1.44269504089f

DEV u16 f2bf(float f) {
    u32 u = __float_as_uint(f);
    return (u16)((u + 0x7FFFu + ((u >> 16) & 1u)) >> 16);
}
DEV float bf2f(u16 h) { return __uint_as_float(((u32)h) << 16); }
DEV float frcp(float x) { return __builtin_amdgcn_rcpf(x); }
DEV float fexp2(float x) {
#if __has_builtin(__builtin_amdgcn_exp2f)
    return __builtin_amdgcn_exp2f(x);
#else
    return exp2f(x);
#endif
}
DEV u32 pack_bf16(float a, float b) {
#if __has_builtin(__builtin_amdgcn_cvt_pk_bf16_f32)
    auto v = __builtin_amdgcn_cvt_pk_bf16_f32(a, b);   // lo=a, hi=b
    u32 r; __builtin_memcpy(&r, &v, 4); return r;
#else
    return (u32)f2bf(a) | ((u32)f2bf(b) << 16);
#endif
}
// extract r-th bf16 (r constant under unroll) from packed uint2
DEV float xex(uint2 v, int r) {
    u32 u = (r & 2) ? v.y : v.x;
    return (r & 1) ? __uint_as_float(u & 0xFFFF0000u) : __uint_as_float(u << 16);
}

// packed-pair helpers (numerics identical to scalar; pk ops where they exist)
DEV f32x2 exp2p(f32x2 a) { f32x2 r; r.x = fexp2(a.x); r.y = fexp2(a.y); return r; }
DEV f32x2 rcpp(f32x2 a)  { f32x2 r; r.x = frcp(a.x);  r.y = frcp(a.y);  return r; }
DEV f32x2 minp(f32x2 a, float b) { f32x2 r; r.x = fminf(a.x, b); r.y = fminf(a.y, b); return r; }
DEV f32x2 LOp(f32x4 v) { f32x2 r; r.x = v[0]; r.y = v[1]; return r; }
DEV f32x2 HIp(f32x4 v) { f32x2 r; r.x = v[2]; r.y = v[3]; return r; }

// one LSTM elementwise step on a PAIR of channels (same expressions / op order
// as the proven scalar version)
DEV f32x2 lstm_pair(f32x2 zi, f32x2 zf, f32x2 zg, f32x2 zo, f32x2* cst) {
    f32x2 ei = exp2p(-zi);
    f32x2 ef = exp2p(-zf);
    f32x2 eo = exp2p(-zo);
    f32x2 eg = exp2p(minp(zg + zg, 115.f));
    f32x2 A = 1.f + ei, F = 1.f + ef, G = eg + 1.f, O = 1.f + eo;
    f32x2 AG = A * G;
    f32x2 cc = (*cst * AG + (eg - 1.f) * F) * rcpp(F * AG);
    *cst = cc;
    f32x2 ec = exp2p(minp(cc * 2.885390082f, 115.f));
    return (ec - 1.f) * rcpp(O * (ec + 1.f));
}

// ---------------------------------------------------------------------------
// K1 (R5-proven): fused embedding gather + input projection, MFMA, both dirs.
// 256 blocks = 2 dirs x 128 chunks of 4 s-steps; each block covers all 64
// batch (4 N-tiles).  X layout = C-frag-swizzled; pre-scaled by log2e.
// ---------------------------------------------------------------------------
__global__ __launch_bounds__(512) void k_inproj2(
    const int* __restrict__ sent, const float* __restrict__ emb,
    const float* __restrict__ wihf, const float* __restrict__ bihf, const float* __restrict__ bhhf,
    const float* __restrict__ wihb, const float* __restrict__ bihb, const float* __restrict__ bhhb,
    u16* __restrict__ Xf, u16* __restrict__ Xb)
{
    int blk = blockIdx.x;
    int d  = blk >> 7;
    int sc = blk & 127;                    // 4 s-steps per block
    const float* wih = d ? wihb : wihf;
    const float* bih = d ? bihb : bihf;
    const float* bhh = d ? bhhb : bhhf;
    u16* X = d ? Xb : Xf;
    int tid = threadIdx.x;
    int w = tid >> 6, lane = tid & 63;
    int rg = lane >> 4, cn = lane & 15;

    short8 afr[4][4];                      // A[m=lane&15][k=(lane>>4)*8+j]
    #pragma unroll
    for (int mi = 0; mi < 4; ++mi) {
        int gate = 16 * (w + 8 * mi) + cn;
        #pragma unroll
        for (int kt = 0; kt < 4; ++kt) {
            const float* p = wih + (size_t)gate * 128 + kt * 32 + rg * 8;
            float4 f0 = *(const float4*)p;
            float4 f1 = *(const float4*)(p + 4);
            union { short8 v; u32 u[4]; } sv;
            sv.u[0] = pack_bf16(f0.x, f0.y);
            sv.u[1] = pack_bf16(f0.z, f0.w);
            sv.u[2] = pack_bf16(f1.x, f1.y);
            sv.u[3] = pack_bf16(f1.z, f1.w);
            afr[mi][kt] = sv.v;
        }
    }
    float bs[4][4];
    #pragma unroll
    for (int mi = 0; mi < 4; ++mi)
        #pragma unroll
        for (int r = 0; r < 4; ++r) {
            int g = 16 * (w + 8 * mi) + 4 * rg + r;
            bs[mi][r] = bih[g] + bhh[g];
        }

    __shared__ u16 tile[2][64][136];       // 2 s-steps x 64 batch x 128 ch
    #pragma unroll
    for (int stage = 0; stage < 2; ++stage) {
        if (stage) __syncthreads();        // protect LDS reuse
        {
            int row = tid >> 2, q = tid & 3;   // 128 rows (2s x 64b), 32 ch each
            int sl = row >> 6, bb = row & 63;
            int tok = sent[(sc * 4 + stage * 2 + sl) * 64 + bb];
            const float* er = emb + (size_t)tok * 128 + q * 32;
            u16* dst = &tile[sl][bb][q * 32];
            #pragma unroll
            for (int u = 0; u < 4; ++u) {
                float4 a = *(const float4*)(er + u * 8);
                float4 c = *(const float4*)(er + u * 8 + 4);
                uint4 st;
                st.x = pack_bf16(a.x, a.y); st.y = pack_bf16(a.z, a.w);
                st.z = pack_bf16(c.x, c.y); st.w = pack_bf16(c.z, c.w);
                *(uint4*)(dst + u * 8) = st;
            }
        }
        __syncthreads();
        #pragma unroll
        for (int ss = 0; ss < 2; ++ss) {
            int s = sc * 4 + stage * 2 + ss;
            #pragma unroll
            for (int nt = 0; nt < 4; ++nt) {       // N-tile = batch group g4
                short8 bfr[4];
                #pragma unroll
                for (int kt = 0; kt < 4; ++kt)
                    bfr[kt] = *(const short8*)&tile[ss][nt * 16 + cn][kt * 32 + rg * 8];
                #pragma unroll
                for (int mi = 0; mi < 4; ++mi) {
                    f32x4 acc = {0.f, 0.f, 0.f, 0.f};
                    #pragma unroll
                    for (int kt = 0; kt < 4; ++kt)
                        acc = __builtin_amdgcn_mfma_f32_16x16x32_bf16(afr[mi][kt], bfr[kt], acc, 0, 0, 0);
                    size_t base = (((size_t)s * 4 + nt) * 32 + (w + 8 * mi)) * 256
                                + (size_t)rg * 64 + (size_t)cn * 4;
                    uint2 st;
                    st.x = pack_bf16((acc[0] + bs[mi][0]) * LOG2E, (acc[1] + bs[mi][1]) * LOG2E);
                    st.y = pack_bf16((acc[2] + bs[mi][2]) * LOG2E, (acc[3] + bs[mi][3]) * LOG2E);
                    *(uint2*)(X + base) = st;
                }
            }
        }
    }
}

// ---------------------------------------------------------------------------
// K2 (R12): R4-proven 8-wave structure + split accumulators.  The 4 K-chunk
// MFMAs per tile were acc-chained (4-deep dependency, ~4x MFMA latency on the
// per-step critical path); now 4 independent accs (a0 init from X, a1..a3
// zero) summed with 2 levels of v_pk_add_f32.  Pair-A h write issues before
// pair-B nonlin so the LDS write drains under B's trans chain.  Nonlin math
// itself (lstm_pair) unchanged.
// ---------------------------------------------------------------------------
__global__ __launch_bounds__(512) void k_lstm(
    const float* __restrict__ h0, const float* __restrict__ c0,
    const float* __restrict__ whhf, const float* __restrict__ whhb,
    const u16* __restrict__ Xf, const u16* __restrict__ Xb,
    u16* __restrict__ hfo, u16* __restrict__ hbo)
{
    int d  = blockIdx.x >> 2, g4 = blockIdx.x & 3;
    const float* whh = d ? whhb : whhf;
    const u16*   X   = d ? Xb   : Xf;
    u16*         ho  = d ? hbo  : hfo;
    int w = threadIdx.x >> 6, lane = threadIdx.x & 63;
    int rg = lane >> 4, cn = lane & 15;

    short8 afr[4][4];                  // whh * log2e, A-frag layout
    #pragma unroll
    for (int mi = 0; mi < 4; ++mi) {
        int gate = 16 * (w + 8 * mi) + cn;
        #pragma unroll
        for (int kt = 0; kt < 4; ++kt) {
            const float* p = whh + (size_t)gate * 128 + kt * 32 + rg * 8;
            float4 f0 = *(const float4*)p;
            float4 f1 = *(const float4*)(p + 4);
            union { short8 v; u32 u[4]; } sv;
            sv.u[0] = pack_bf16(f0.x * LOG2E, f0.y * LOG2E);
            sv.u[1] = pack_bf16(f0.z * LOG2E, f0.w * LOG2E);
            sv.u[2] = pack_bf16(f1.x * LOG2E, f1.y * LOG2E);
            sv.u[3] = pack_bf16(f1.z * LOG2E, f1.w * LOG2E);
            afr[mi][kt] = sv.v;
        }
    }
    int b = g4 * 16 + cn;
    int chb = 16 * w + rg * 4;
    f32x2 cst01, cst23;
    {
        float4 cv = *(const float4*)(c0 + ((size_t)d * 64 + b) * 128 + chb);
        cst01.x = cv.x; cst01.y = cv.y;
        cst23.x = cv.z; cst23.y = cv.w;
    }
    __shared__ u16 hbuf[2][16][136];
    {
        float4 hv = *(const float4*)(h0 + ((size_t)d * 64 + b) * 128 + chb);
        uint2 st0;
        st0.x = pack_bf16(hv.x, hv.y);
        st0.y = pack_bf16(hv.z, hv.w);
        *(uint2*)&hbuf[0][cn][chb] = st0;
    }
    __syncthreads();

    int s0 = d ? 511 : 0;
    const int sdelta = d ? -32768 : 32768;      // X u16 elems per s-step
    const ptrdiff_t hdelta = d ? -8192 : 8192;  // 64*128 u16 per s-step
    size_t lof = (size_t)rg * 64 + (size_t)cn * 4;

    const u16* pa[4]; const u16* pb[4];
    uint2 xA[4], xB[4];
    #pragma unroll
    for (int mi = 0; mi < 4; ++mi) {
        const u16* base = X + (((size_t)s0 * 4 + g4) * 32 + (w + 8 * mi)) * 256 + lof;
        xA[mi] = *(const uint2*)base;
        xB[mi] = *(const uint2*)(base + sdelta);
        pa[mi] = base + 2 * sdelta;
        pb[mi] = base + 3 * sdelta;
    }
    u16* hop = ho + ((size_t)s0 * 64 + b) * 128 + chb;

#define LSTM_STEP(RB, WB, XC, XP)                                            \
    do {                                                                     \
        short8 bfr[4];                                                       \
        _Pragma("unroll")                                                    \
        for (int kt = 0; kt < 4; ++kt)                                       \
            bfr[kt] = *(const short8*)&hbuf[RB][cn][kt * 32 + rg * 8];       \
        f32x4 z[4];                                                          \
        _Pragma("unroll")                                                    \
        for (int mi = 0; mi < 4; ++mi) {                                     \
            f32x4 a0, a1, a2, a3;                                            \
            a0[0] = xex(XC[mi], 0); a0[1] = xex(XC[mi], 1);                  \
            a0[2] = xex(XC[mi], 2); a0[3] = xex(XC[mi], 3);                  \
            a1 = (f32x4){0.f, 0.f, 0.f, 0.f};                                \
            a2 = (f32x4){0.f, 0.f, 0.f, 0.f};                                \
            a3 = (f32x4){0.f, 0.f, 0.f, 0.f};                                \
            a0 = __builtin_amdgcn_mfma_f32_16x16x32_bf16(                    \
                afr[mi][0], bfr[0], a0, 0, 0, 0);                            \
            a1 = __builtin_amdgcn_mfma_f32_16x16x32_bf16(                    \
                afr[mi][1], bfr[1], a1, 0, 0, 0);                            \
            a2 = __builtin_amdgcn_mfma_f32_16x16x32_bf16(                    \
                afr[mi][2], bfr[2], a2, 0, 0, 0);                            \
            a3 = __builtin_amdgcn_mfma_f32_16x16x32_bf16(                    \
                afr[mi][3], bfr[3], a3, 0, 0, 0);                            \
            z[mi] = (a0 + a1) + (a2 + a3);                                   \
            XC[mi] = *(const uint2*)XP[mi];                                  \
            XP[mi] += 2 * sdelta;                                            \
        }                                                                    \
        f32x2 h01 = lstm_pair(LOp(z[0]), LOp(z[1]),                          \
                              LOp(z[2]), LOp(z[3]), &cst01);                 \
        u32 pA = pack_bf16(h01.x, h01.y);                                    \
        *(u32*)&hbuf[WB][cn][chb] = pA;                                      \
        *(u32*)hop = pA;                                                     \
        f32x2 h23 = lstm_pair(HIp(z[0]), HIp(z[1]),                          \
                              HIp(z[2]), HIp(z[3]), &cst23);                 \
        u32 pB = pack_bf16(h23.x, h23.y);                                    \
        *(u32*)&hbuf[WB][cn][chb + 2] = pB;                                  \
        *(u32*)(hop + 2) = pB;                                               \
        hop += hdelta;                                                       \
        asm volatile("s_waitcnt lgkmcnt(0)\n\ts_barrier" ::: "memory");      \
    } while (0)

    for (int it = 0; it < 256; ++it) {
        LSTM_STEP(0, 1, xA, pa);
        LSTM_STEP(1, 0, xB, pb);
    }
#undef LSTM_STEP
}

// ---------------------------------------------------------------------------
// K3: feats[s,b,t] = [hf|hb] . w_out[t] + b_out[t].   block handles 32 pos.
// Paired reads (u32 for bf16 pairs, float2 for weights) halve LDS insts.
// ---------------------------------------------------------------------------
__global__ __launch_bounds__(256) void k_feats(
    const u16* __restrict__ hf, const u16* __restrict__ hb,
    const float* __restrict__ wout, const float* __restrict__ bout,
    float* __restrict__ feats)
{
    __shared__ u16 sf[32][136], sb[32][136];
    __shared__ float wo[7][260];
    __shared__ float bo[8];
    int tid = threadIdx.x;
    int pos0 = blockIdx.x * 32;
    {
        int r = tid >> 3, cc = (tid & 7) * 16;
        const uint4* pf = (const uint4*)(hf + (size_t)(pos0 + r) * 128 + cc);
        const uint4* pb = (const uint4*)(hb + (size_t)(pos0 + r) * 128 + cc);
        *(uint4*)&sf[r][cc]     = pf[0];
        *(uint4*)&sf[r][cc + 8] = pf[1];
        *(uint4*)&sb[r][cc]     = pb[0];
        *(uint4*)&sb[r][cc + 8] = pb[1];
    }
    for (int i = tid; i < 1792; i += 256) wo[i >> 8][i & 255] = wout[i];
    if (tid < 7) bo[tid] = bout[tid];
    __syncthreads();
    int pp = tid >> 3, tt = tid & 7;
    if (tt < 7) {
        float acc = bo[tt];
        #pragma unroll 4
        for (int ch = 0; ch < 128; ch += 2) {
            u32 uf = *(const u32*)&sf[pp][ch];
            u32 ub = *(const u32*)&sb[pp][ch];
            float2 w0 = *(const float2*)&wo[tt][ch];
            float2 w1 = *(const float2*)&wo[tt][128 + ch];
            acc += __uint_as_float(uf << 16) * w0.x
                 + __uint_as_float(uf & 0xFFFF0000u) * w0.y
                 + __uint_as_float(ub << 16) * w1.x
                 + __uint_as_float(ub & 0xFFFF0000u) * w1.y;
        }
        feats[(size_t)(pos0 + pp) * 7 + tt] = acc;
    }
}

// ---------------------------------------------------------------------------
// K4a: CRF chunk fold.  block=(b, chunk of 64 steps).  512 blocks.
// ---------------------------------------------------------------------------
__global__ __launch_bounds__(64) void k_crf_chunk(
    const float* __restrict__ feats, const float* __restrict__ trans,
    float* __restrict__ chunkM)
{
    int b = blockIdx.x >> 3, c = blockIdx.x & 7;
    int lane = threadIdx.x;
    int i = lane >> 3, j = lane & 7;
    __shared__ float M[8][8];
    __shared__ float fl[64][8];
    int s0 = c * 64;
    for (int idx = lane; idx < 448; idx += 64) {
        int ss = idx / 7, jj = idx - ss * 7;
        fl[ss][jj] = feats[(size_t)((s0 + ss) * 64 + b) * 7 + jj];
    }
    float tc[7];
    #pragma unroll
    for (int k = 0; k < 7; ++k) tc[k] = (j < 7) ? trans[k * 7 + j] : 0.f;
    __syncthreads();
    M[i][j] = (i < 7 && j < 7) ? (trans[i * 7 + j] + fl[0][j]) : -1e30f;
    __syncthreads();
    for (int ss = 1; ss < 64; ++ss) {
        float4 m0 = *(const float4*)&M[i][0];
        float4 m1 = *(const float4*)&M[i][4];
        float v0 = m0.x + tc[0], v1 = m0.y + tc[1], v2 = m0.z + tc[2];
        float v3 = m0.w + tc[3], v4 = m1.x + tc[4], v5 = m1.y + tc[5];
        float v6 = m1.z + tc[6];
        float mx = fmaxf(fmaxf(fmaxf(v0, v1), fmaxf(v2, v3)),
                         fmaxf(fmaxf(v4, v5), v6));
        float sm = __expf(v0 - mx) + __expf(v1 - mx) + __expf(v2 - mx)
                 + __expf(v3 - mx) + __expf(v4 - mx) + __expf(v5 - mx)
                 + __expf(v6 - mx);
        float r = mx + __logf(sm) + fl[ss][j];
        __syncthreads();
        if (i < 7 && j < 7) M[i][j] = r;
        __syncthreads();
    }
    if (i < 7 && j < 7)
        chunkM[(size_t)(b * 8 + c) * 49 + i * 7 + j] = M[i][j];
}

// ---------------------------------------------------------------------------
// K4b: SINGLE-block final fold.  8 waves x 8 batches; lane = k*8+j
// handles (batch w*8+k, tag j).  Folds 8 chunk matrices via shuffle-lse,
// adds STOP row, computes gold with all 512 threads, block-reduces, and
// writes d_out[0] with a plain store (no memset node, no atomic).
// ---------------------------------------------------------------------------
__global__ __launch_bounds__(512) void k_crf_final(
    const float* __restrict__ chunkM, const float* __restrict__ trans,
    const int* __restrict__ tags, const float* __restrict__ feats,
    float* __restrict__ out)
{
    int tid = threadIdx.x;
    int w = tid >> 6, lane = tid & 63;
    int k = lane >> 3, j = lane & 7;
    int b = w * 8 + k;
    bool jv = (j < 7);
    __shared__ float Tl[49];
    __shared__ float red[512];
    __shared__ float fsh[64];
    if (tid < 49) Tl[tid] = trans[tid];
    __syncthreads();

    float av = (j == 5) ? 0.f : -1e4f;          // alpha0
    #pragma unroll
    for (int c = 0; c < 8; ++c) {
        float a0 = __shfl(av, k * 8 + 0, 64);
        float a1 = __shfl(av, k * 8 + 1, 64);
        float a2 = __shfl(av, k * 8 + 2, 64);
        float a3 = __shfl(av, k * 8 + 3, 64);
        float a4 = __shfl(av, k * 8 + 4, 64);
        float a5 = __shfl(av, k * 8 + 5, 64);
        float a6 = __shfl(av, k * 8 + 6, 64);
        if (jv) {
            const float* Pp = chunkM + ((size_t)b * 8 + c) * 49 + j;
            float v0 = a0 + Pp[0],  v1 = a1 + Pp[7],  v2 = a2 + Pp[14];
            float v3 = a3 + Pp[21], v4 = a4 + Pp[28], v5 = a5 + Pp[35];
            float v6 = a6 + Pp[42];
            float mx = fmaxf(fmaxf(fmaxf(v0, v1), fmaxf(v2, v3)),
                             fmaxf(fmaxf(v4, v5), v6));
            float sm = __expf(v0 - mx) + __expf(v1 - mx) + __expf(v2 - mx)
                     + __expf(v3 - mx) + __expf(v4 - mx) + __expf(v5 - mx)
                     + __expf(v6 - mx);
            av = mx + __logf(sm);
        }
    }
    // fwd = lse_j(av[j] + trans[STOP=6][j]) over the 8-lane j-group
    float u = jv ? (av + Tl[42 + j]) : -1e30f;
    float m = u;
    #pragma unroll
    for (int off = 1; off < 8; off <<= 1) m = fmaxf(m, __shfl_xor(m, off, 64));
    float e = jv ? __expf(u - m) : 0.f;
    #pragma unroll
    for (int off = 1; off < 8; off <<= 1) e += __shfl_xor(e, off, 64);
    float fwd = m + __logf(e);
    if (j == 0) fsh[b] = fwd;

    // gold: thread handles batch tb, quarter q (64 steps each)
    int tb = tid & 63, q = tid >> 6;
    const int* tgp = tags + (size_t)tb * 512;
    float acc = 0.f;
    int tp = (q == 0) ? 5 : tgp[q * 64 - 1];
    for (int ss = q * 64; ss < q * 64 + 64; ++ss) {
        int tn = tgp[ss];
        acc += Tl[tn * 7 + tp] + feats[(size_t)(ss * 64 + tb) * 7 + tn];
        tp = tn;
    }
    if (q == 7) acc += Tl[42 + tgp[511]];
    red[tid] = acc;
    __syncthreads();
    if (tid < 64) {
        float g = red[tid];
        #pragma unroll
        for (int qq = 1; qq < 8; ++qq) g += red[tid + 64 * qq];
        red[tid] = fsh[tid] - g;
    }
    __syncthreads();
    if (tid < 64) {
        float v = red[tid];
        #pragma unroll
        for (int off = 1; off < 64; off <<= 1) v += __shfl_xor(v, off, 64);
        if (tid == 0) out[0] = v * (1.0f / 64.0f);
    }
}

// ---------------------------------------------------------------------------
extern "C" void kernel_launch(void* const* d_in, const int* in_sizes, int n_in,
                              void* d_out, int out_size, void* d_ws, size_t ws_size,
                              hipStream_t stream) {
    const int*   sent = (const int*)d_in[0];
    const int*   tags = (const int*)d_in[1];
    const float* h0   = (const float*)d_in[2];
    const float* c0   = (const float*)d_in[3];
    const float* emb  = (const float*)d_in[4];
    const float* wihf = (const float*)d_in[5];
    const float* whhf = (const float*)d_in[6];
    const float* bihf = (const float*)d_in[7];
    const float* bhhf = (const float*)d_in[8];
    const float* wihb = (const float*)d_in[9];
    const float* whhb = (const float*)d_in[10];
    const float* bihb = (const float*)d_in[11];
    const float* bhhb = (const float*)d_in[12];
    const float* wout = (const float*)d_in[13];
    const float* bout = (const float*)d_in[14];
    const float* trn  = (const float*)d_in[15];

    char* ws = (char*)d_ws;
    u16*   Xf     = (u16*)(ws);                       // 33,554,432 B
    u16*   Xb     = (u16*)(ws + 33554432);            // 33,554,432 B
    u16*   hfp    = (u16*)(ws + 67108864);            //  8,388,608 B
    u16*   hbp    = (u16*)(ws + 75497472);            //  8,388,608 B
    float* feats  = (float*)(ws + 83886080);          //    917,504 B
    float* chunkM = (float*)(ws + 84803584);          //    100,352 B

    k_inproj2<<<256, 512, 0, stream>>>(sent, emb, wihf, bihf, bhhf,
                                       wihb, bihb, bhhb, Xf, Xb);
    k_lstm<<<8, 512, 0, stream>>>(h0, c0, whhf, whhb, Xf, Xb, hfp, hbp);
    k_feats<<<1024, 256, 0, stream>>>(hfp, hbp, wout, bout, feats);
    k_crf_chunk<<<512, 64, 0, stream>>>(feats, trn, chunkM);
    k_crf_final<<<1, 512, 0, stream>>>(chunkM, trn, tags, feats, (float*)d_out);
}

// Round 6
// 560.974 us; speedup vs baseline: 1.3688x; 1.1187x over previous
//
#include <hip/hip_runtime.h>

typedef unsigned int u32;
typedef unsigned short u16;
typedef __attribute__((ext_vector_type(8))) short short8;   // 8 bf16 (4 VGPRs)
typedef __attribute__((ext_vector_type(4))) float f32x4;
typedef __attribute__((ext_vector_type(2))) float f32x2;

#define DEV __device__ __forceinline__
#define LOG2E 1.44269504089f

DEV u16 f2bf(float f) {
    u32 u = __float_as_uint(f);
    return (u16)((u + 0x7FFFu + ((u >> 16) & 1u)) >> 16);
}
DEV float bf2f(u16 h) { return __uint_as_float(((u32)h) << 16); }
DEV float frcp(float x) { return __builtin_amdgcn_rcpf(x); }
DEV float fexp2(float x) {
#if __has_builtin(__builtin_amdgcn_exp2f)
    return __builtin_amdgcn_exp2f(x);
#else
    return exp2f(x);
#endif
}
DEV u32 pack_bf16(float a, float b) {
#if __has_builtin(__builtin_amdgcn_cvt_pk_bf16_f32)
    auto v = __builtin_amdgcn_cvt_pk_bf16_f32(a, b);   // lo=a, hi=b
    u32 r; __builtin_memcpy(&r, &v, 4); return r;
#else
    return (u32)f2bf(a) | ((u32)f2bf(b) << 16);
#endif
}
// extract r-th bf16 (r constant under unroll) from packed uint2
DEV float xex(uint2 v, int r) {
    u32 u = (r & 2) ? v.y : v.x;
    return (r & 1) ? __uint_as_float(u & 0xFFFF0000u) : __uint_as_float(u << 16);
}

// Gate-row permutation (R13): new row g' (bit layout [mi:2][w:3][rg:2][r:2])
// maps to old gate = type r, channel 16w+4rg+mi.  Tile mi's 16 rows become
// {4 types x 4 channels}; each thread's 4 acc elements of ONE tile are
// {zi,zf,zg,zo} of ONE channel; thread's channels across tiles stay the
// CONTIGUOUS quad chb..chb+3 (write pattern identical to the proven R2).
// Nonlin of channels (chb,chb+1) depends only on tiles 0,1 -> overlaps the
// MFMAs of tiles 2,3.  Applied to weight rows + biases in BOTH kernels.
DEV int gmap2(int g) { return ((g & 3) << 7) + (g & 0x7C) + (g >> 7); }

// packed-pair helpers (numerics identical to scalar; pk ops where they exist)
DEV f32x2 exp2p(f32x2 a) { f32x2 r; r.x = fexp2(a.x); r.y = fexp2(a.y); return r; }
DEV f32x2 rcpp(f32x2 a)  { f32x2 r; r.x = frcp(a.x);  r.y = frcp(a.y);  return r; }
DEV f32x2 minp(f32x2 a, float b) { f32x2 r; r.x = fminf(a.x, b); r.y = fminf(a.y, b); return r; }

// one LSTM elementwise step on a PAIR of channels (same expressions / op order
// as the proven scalar version)
DEV f32x2 lstm_pair(f32x2 zi, f32x2 zf, f32x2 zg, f32x2 zo, f32x2* cst) {
    f32x2 ei = exp2p(-zi);
    f32x2 ef = exp2p(-zf);
    f32x2 eo = exp2p(-zo);
    f32x2 eg = exp2p(minp(zg + zg, 115.f));
    f32x2 A = 1.f + ei, F = 1.f + ef, G = eg + 1.f, O = 1.f + eo;
    f32x2 AG = A * G;
    f32x2 cc = (*cst * AG + (eg - 1.f) * F) * rcpp(F * AG);
    *cst = cc;
    f32x2 ec = exp2p(minp(cc * 2.885390082f, 115.f));
    return (ec - 1.f) * rcpp(O * (ec + 1.f));
}

// ---------------------------------------------------------------------------
// K1: fused embedding gather + input projection, MFMA, both dirs.
// 256 blocks = 2 dirs x 128 chunks of 4 s-steps.  X layout = C-frag-swizzled
// in gmap2 row order; pre-scaled by log2e.
// ---------------------------------------------------------------------------
__global__ __launch_bounds__(512) void k_inproj2(
    const int* __restrict__ sent, const float* __restrict__ emb,
    const float* __restrict__ wihf, const float* __restrict__ bihf, const float* __restrict__ bhhf,
    const float* __restrict__ wihb, const float* __restrict__ bihb, const float* __restrict__ bhhb,
    u16* __restrict__ Xf, u16* __restrict__ Xb)
{
    int blk = blockIdx.x;
    int d  = blk >> 7;
    int sc = blk & 127;                    // 4 s-steps per block
    const float* wih = d ? wihb : wihf;
    const float* bih = d ? bihb : bihf;
    const float* bhh = d ? bhhb : bhhf;
    u16* X = d ? Xb : Xf;
    int tid = threadIdx.x;
    int w = tid >> 6, lane = tid & 63;
    int rg = lane >> 4, cn = lane & 15;

    short8 afr[4][4];                      // A[m=lane&15][k=(lane>>4)*8+j]
    #pragma unroll
    for (int mi = 0; mi < 4; ++mi) {
        int gate = gmap2(16 * (w + 8 * mi) + cn);   // permuted row
        #pragma unroll
        for (int kt = 0; kt < 4; ++kt) {
            const float* p = wih + (size_t)gate * 128 + kt * 32 + rg * 8;
            float4 f0 = *(const float4*)p;
            float4 f1 = *(const float4*)(p + 4);
            union { short8 v; u32 u[4]; } sv;
            sv.u[0] = pack_bf16(f0.x, f0.y);
            sv.u[1] = pack_bf16(f0.z, f0.w);
            sv.u[2] = pack_bf16(f1.x, f1.y);
            sv.u[3] = pack_bf16(f1.z, f1.w);
            afr[mi][kt] = sv.v;
        }
    }
    float bs[4][4];
    #pragma unroll
    for (int mi = 0; mi < 4; ++mi)
        #pragma unroll
        for (int r = 0; r < 4; ++r) {
            int g = gmap2(16 * (w + 8 * mi) + 4 * rg + r);
            bs[mi][r] = bih[g] + bhh[g];
        }

    __shared__ u16 tile[2][64][136];       // 2 s-steps x 64 batch x 128 ch
    #pragma unroll
    for (int stage = 0; stage < 2; ++stage) {
        if (stage) __syncthreads();        // protect LDS reuse
        {
            int row = tid >> 2, q = tid & 3;   // 128 rows (2s x 64b), 32 ch each
            int sl = row >> 6, bb = row & 63;
            int tok = sent[(sc * 4 + stage * 2 + sl) * 64 + bb];
            const float* er = emb + (size_t)tok * 128 + q * 32;
            u16* dst = &tile[sl][bb][q * 32];
            #pragma unroll
            for (int u = 0; u < 4; ++u) {
                float4 a = *(const float4*)(er + u * 8);
                float4 c = *(const float4*)(er + u * 8 + 4);
                uint4 st;
                st.x = pack_bf16(a.x, a.y); st.y = pack_bf16(a.z, a.w);
                st.z = pack_bf16(c.x, c.y); st.w = pack_bf16(c.z, c.w);
                *(uint4*)(dst + u * 8) = st;
            }
        }
        __syncthreads();
        #pragma unroll
        for (int ss = 0; ss < 2; ++ss) {
            int s = sc * 4 + stage * 2 + ss;
            #pragma unroll
            for (int nt = 0; nt < 4; ++nt) {       // N-tile = batch group g4
                short8 bfr[4];
                #pragma unroll
                for (int kt = 0; kt < 4; ++kt)
                    bfr[kt] = *(const short8*)&tile[ss][nt * 16 + cn][kt * 32 + rg * 8];
                #pragma unroll
                for (int mi = 0; mi < 4; ++mi) {
                    f32x4 acc = {0.f, 0.f, 0.f, 0.f};
                    #pragma unroll
                    for (int kt = 0; kt < 4; ++kt)
                        acc = __builtin_amdgcn_mfma_f32_16x16x32_bf16(afr[mi][kt], bfr[kt], acc, 0, 0, 0);
                    size_t base = (((size_t)s * 4 + nt) * 32 + (w + 8 * mi)) * 256
                                + (size_t)rg * 64 + (size_t)cn * 4;
                    uint2 st;
                    st.x = pack_bf16((acc[0] + bs[mi][0]) * LOG2E, (acc[1] + bs[mi][1]) * LOG2E);
                    st.y = pack_bf16((acc[2] + bs[mi][2]) * LOG2E, (acc[3] + bs[mi][3]) * LOG2E);
                    *(uint2*)(X + base) = st;
                }
            }
        }
    }
}

// ---------------------------------------------------------------------------
// K2 (R13): R2-proven 8-wave structure + gmap2 tiling.  Thread's tile mi
// yields {zi,zf,zg,zo} of channel chb+mi (contiguous quad, same write
// pattern as R2).  Nonlin of pair (chb,chb+1) depends only on tiles 0,1 ->
// its trans chain overlaps tiles 2,3's MFMAs.  MFMA acc stays K-chained
// (R12 proved chaining is free on the matrix pipe).
// ---------------------------------------------------------------------------
__global__ __launch_bounds__(512) void k_lstm(
    const float* __restrict__ h0, const float* __restrict__ c0,
    const float* __restrict__ whhf, const float* __restrict__ whhb,
    const u16* __restrict__ Xf, const u16* __restrict__ Xb,
    u16* __restrict__ hfo, u16* __restrict__ hbo)
{
    int d  = blockIdx.x >> 2, g4 = blockIdx.x & 3;
    const float* whh = d ? whhb : whhf;
    const u16*   X   = d ? Xb   : Xf;
    u16*         ho  = d ? hbo  : hfo;
    int w = threadIdx.x >> 6, lane = threadIdx.x & 63;
    int rg = lane >> 4, cn = lane & 15;

    short8 afr[4][4];                  // whh * log2e, A-frag layout (gmap2 rows)
    #pragma unroll
    for (int mi = 0; mi < 4; ++mi) {
        int gate = gmap2(16 * (w + 8 * mi) + cn);
        #pragma unroll
        for (int kt = 0; kt < 4; ++kt) {
            const float* p = whh + (size_t)gate * 128 + kt * 32 + rg * 8;
            float4 f0 = *(const float4*)p;
            float4 f1 = *(const float4*)(p + 4);
            union { short8 v; u32 u[4]; } sv;
            sv.u[0] = pack_bf16(f0.x * LOG2E, f0.y * LOG2E);
            sv.u[1] = pack_bf16(f0.z * LOG2E, f0.w * LOG2E);
            sv.u[2] = pack_bf16(f1.x * LOG2E, f1.y * LOG2E);
            sv.u[3] = pack_bf16(f1.z * LOG2E, f1.w * LOG2E);
            afr[mi][kt] = sv.v;
        }
    }
    int b = g4 * 16 + cn;
    int chb = 16 * w + rg * 4;         // thread's channel quad (same as R2)
    f32x2 cstA, cstB;                  // c for (chb,chb+1) / (chb+2,chb+3)
    {
        float4 cv = *(const float4*)(c0 + ((size_t)d * 64 + b) * 128 + chb);
        cstA.x = cv.x; cstA.y = cv.y;
        cstB.x = cv.z; cstB.y = cv.w;
    }
    __shared__ u16 hbuf[2][16][136];
    {
        float4 hv = *(const float4*)(h0 + ((size_t)d * 64 + b) * 128 + chb);
        uint2 st0;
        st0.x = pack_bf16(hv.x, hv.y);
        st0.y = pack_bf16(hv.z, hv.w);
        *(uint2*)&hbuf[0][cn][chb] = st0;
    }
    __syncthreads();

    int s0 = d ? 511 : 0;
    const int sdelta = d ? -32768 : 32768;      // X u16 elems per s-step
    const ptrdiff_t hdelta = d ? -8192 : 8192;  // 64*128 u16 per s-step
    size_t lof = (size_t)rg * 64 + (size_t)cn * 4;

    const u16* pa[4]; const u16* pb[4];
    uint2 xA[4], xB[4];
    #pragma unroll
    for (int mi = 0; mi < 4; ++mi) {
        const u16* base = X + (((size_t)s0 * 4 + g4) * 32 + (w + 8 * mi)) * 256 + lof;
        xA[mi] = *(const uint2*)base;
        xB[mi] = *(const uint2*)(base + sdelta);
        pa[mi] = base + 2 * sdelta;
        pb[mi] = base + 3 * sdelta;
    }
    u16* hop = ho + ((size_t)s0 * 64 + b) * 128 + chb;

#define LSTM_STEP(RB, WB, XC, XP)                                            \
    do {                                                                     \
        short8 bfr[4];                                                       \
        _Pragma("unroll")                                                    \
        for (int kt = 0; kt < 4; ++kt)                                       \
            bfr[kt] = *(const short8*)&hbuf[RB][cn][kt * 32 + rg * 8];       \
        f32x4 z[4];                                                          \
        _Pragma("unroll")                                                    \
        for (int mi = 0; mi < 4; ++mi) {                                     \
            f32x4 acc;                                                       \
            acc[0] = xex(XC[mi], 0); acc[1] = xex(XC[mi], 1);                \
            acc[2] = xex(XC[mi], 2); acc[3] = xex(XC[mi], 3);                \
            _Pragma("unroll")                                                \
            for (int kt = 0; kt < 4; ++kt)                                   \
                acc = __builtin_amdgcn_mfma_f32_16x16x32_bf16(               \
                    afr[mi][kt], bfr[kt], acc, 0, 0, 0);                     \
            z[mi] = acc;                                                     \
            XC[mi] = *(const uint2*)XP[mi];                                  \
            XP[mi] += 2 * sdelta;                                            \
        }                                                                    \
        f32x2 ziA = {z[0][0], z[1][0]}, zfA = {z[0][1], z[1][1]};            \
        f32x2 zgA = {z[0][2], z[1][2]}, zoA = {z[0][3], z[1][3]};            \
        f32x2 hA = lstm_pair(ziA, zfA, zgA, zoA, &cstA);                     \
        u32 pA = pack_bf16(hA.x, hA.y);                                      \
        *(u32*)&hbuf[WB][cn][chb] = pA;                                      \
        *(u32*)hop = pA;                                                     \
        f32x2 ziB = {z[2][0], z[3][0]}, zfB = {z[2][1], z[3][1]};            \
        f32x2 zgB = {z[2][2], z[3][2]}, zoB = {z[2][3], z[3][3]};            \
        f32x2 hB = lstm_pair(ziB, zfB, zgB, zoB, &cstB);                     \
        u32 pB = pack_bf16(hB.x, hB.y);                                      \
        *(u32*)&hbuf[WB][cn][chb + 2] = pB;                                  \
        *(u32*)(hop + 2) = pB;                                               \
        hop += hdelta;                                                       \
        asm volatile("s_waitcnt lgkmcnt(0)\n\ts_barrier" ::: "memory");      \
    } while (0)

    for (int it = 0; it < 256; ++it) {
        LSTM_STEP(0, 1, xA, pa);
        LSTM_STEP(1, 0, xB, pb);
    }
#undef LSTM_STEP
}

// ---------------------------------------------------------------------------
// K3: feats[s,b,t] = [hf|hb] . w_out[t] + b_out[t].   block handles 32 pos.
// Paired reads (u32 for bf16 pairs, float2 for weights) halve LDS insts.
// ---------------------------------------------------------------------------
__global__ __launch_bounds__(256) void k_feats(
    const u16* __restrict__ hf, const u16* __restrict__ hb,
    const float* __restrict__ wout, const float* __restrict__ bout,
    float* __restrict__ feats)
{
    __shared__ u16 sf[32][136], sb[32][136];
    __shared__ float wo[7][260];
    __shared__ float bo[8];
    int tid = threadIdx.x;
    int pos0 = blockIdx.x * 32;
    {
        int r = tid >> 3, cc = (tid & 7) * 16;
        const uint4* pf = (const uint4*)(hf + (size_t)(pos0 + r) * 128 + cc);
        const uint4* pb = (const uint4*)(hb + (size_t)(pos0 + r) * 128 + cc);
        *(uint4*)&sf[r][cc]     = pf[0];
        *(uint4*)&sf[r][cc + 8] = pf[1];
        *(uint4*)&sb[r][cc]     = pb[0];
        *(uint4*)&sb[r][cc + 8] = pb[1];
    }
    for (int i = tid; i < 1792; i += 256) wo[i >> 8][i & 255] = wout[i];
    if (tid < 7) bo[tid] = bout[tid];
    __syncthreads();
    int pp = tid >> 3, tt = tid & 7;
    if (tt < 7) {
        float acc = bo[tt];
        #pragma unroll 4
        for (int ch = 0; ch < 128; ch += 2) {
            u32 uf = *(const u32*)&sf[pp][ch];
            u32 ub = *(const u32*)&sb[pp][ch];
            float2 w0 = *(const float2*)&wo[tt][ch];
            float2 w1 = *(const float2*)&wo[tt][128 + ch];
            acc += __uint_as_float(uf << 16) * w0.x
                 + __uint_as_float(uf & 0xFFFF0000u) * w0.y
                 + __uint_as_float(ub << 16) * w1.x
                 + __uint_as_float(ub & 0xFFFF0000u) * w1.y;
        }
        feats[(size_t)(pos0 + pp) * 7 + tt] = acc;
    }
}

// ---------------------------------------------------------------------------
// K4a (R13): CRF chunk fold.  block=(b, chunk of 64 steps), 512 blocks of a
// SINGLE wave.  M lives in registers (lane (i,j) holds M[i][j]); row access
// via __shfl.  Removes the per-iter LDS M round-trip and 126 barriers.
// ---------------------------------------------------------------------------
__global__ __launch_bounds__(64) void k_crf_chunk(
    const float* __restrict__ feats, const float* __restrict__ trans,
    float* __restrict__ chunkM)
{
    int b = blockIdx.x >> 3, c = blockIdx.x & 7;
    int lane = threadIdx.x;
    int i = lane >> 3, j = lane & 7;
    __shared__ float fl[64][8];
    int s0 = c * 64;
    for (int idx = lane; idx < 448; idx += 64) {
        int ss = idx / 7, jj = idx - ss * 7;
        fl[ss][jj] = feats[(size_t)((s0 + ss) * 64 + b) * 7 + jj];
    }
    float tc[7];
    #pragma unroll
    for (int k = 0; k < 7; ++k) tc[k] = (j < 7) ? trans[k * 7 + j] : 0.f;
    bool valid = (i < 7 && j < 7);
    float M0 = valid ? trans[i * 7 + j] : -1e30f;
    __syncthreads();
    float M = M0 + (valid ? fl[0][j] : 0.f);
    for (int ss = 1; ss < 64; ++ss) {
        int rb = i * 8;
        float v0 = __shfl(M, rb + 0, 64) + tc[0];
        float v1 = __shfl(M, rb + 1, 64) + tc[1];
        float v2 = __shfl(M, rb + 2, 64) + tc[2];
        float v3 = __shfl(M, rb + 3, 64) + tc[3];
        float v4 = __shfl(M, rb + 4, 64) + tc[4];
        float v5 = __shfl(M, rb + 5, 64) + tc[5];
        float v6 = __shfl(M, rb + 6, 64) + tc[6];
        float mx = fmaxf(fmaxf(fmaxf(v0, v1), fmaxf(v2, v3)),
                         fmaxf(fmaxf(v4, v5), v6));
        float sm = __expf(v0 - mx) + __expf(v1 - mx) + __expf(v2 - mx)
                 + __expf(v3 - mx) + __expf(v4 - mx) + __expf(v5 - mx)
                 + __expf(v6 - mx);
        M = mx + __logf(sm) + fl[ss][j];
    }
    if (valid)
        chunkM[(size_t)(b * 8 + c) * 49 + i * 7 + j] = M;
}

// ---------------------------------------------------------------------------
// K4b: SINGLE-block final fold.  8 waves x 8 batches; lane = k*8+j
// handles (batch w*8+k, tag j).  Folds 8 chunk matrices via shuffle-lse,
// adds STOP row, computes gold with all 512 threads, block-reduces, and
// writes d_out[0] with a plain store (no memset node, no atomic).
// ---------------------------------------------------------------------------
__global__ __launch_bounds__(512) void k_crf_final(
    const float* __restrict__ chunkM, const float* __restrict__ trans,
    const int* __restrict__ tags, const float* __restrict__ feats,
    float* __restrict__ out)
{
    int tid = threadIdx.x;
    int w = tid >> 6, lane = tid & 63;
    int k = lane >> 3, j = lane & 7;
    int b = w * 8 + k;
    bool jv = (j < 7);
    __shared__ float Tl[49];
    __shared__ float red[512];
    __shared__ float fsh[64];
    if (tid < 49) Tl[tid] = trans[tid];
    __syncthreads();

    float av = (j == 5) ? 0.f : -1e4f;          // alpha0
    #pragma unroll
    for (int c = 0; c < 8; ++c) {
        float a0 = __shfl(av, k * 8 + 0, 64);
        float a1 = __shfl(av, k * 8 + 1, 64);
        float a2 = __shfl(av, k * 8 + 2, 64);
        float a3 = __shfl(av, k * 8 + 3, 64);
        float a4 = __shfl(av, k * 8 + 4, 64);
        float a5 = __shfl(av, k * 8 + 5, 64);
        float a6 = __shfl(av, k * 8 + 6, 64);
        if (jv) {
            const float* Pp = chunkM + ((size_t)b * 8 + c) * 49 + j;
            float v0 = a0 + Pp[0],  v1 = a1 + Pp[7],  v2 = a2 + Pp[14];
            float v3 = a3 + Pp[21], v4 = a4 + Pp[28], v5 = a5 + Pp[35];
            float v6 = a6 + Pp[42];
            float mx = fmaxf(fmaxf(fmaxf(v0, v1), fmaxf(v2, v3)),
                             fmaxf(fmaxf(v4, v5), v6));
            float sm = __expf(v0 - mx) + __expf(v1 - mx) + __expf(v2 - mx)
                     + __expf(v3 - mx) + __expf(v4 - mx) + __expf(v5 - mx)
                     + __expf(v6 - mx);
            av = mx + __logf(sm);
        }
    }
    // fwd = lse_j(av[j] + trans[STOP=6][j]) over the 8-lane j-group
    float u = jv ? (av + Tl[42 + j]) : -1e30f;
    float m = u;
    #pragma unroll
    for (int off = 1; off < 8; off <<= 1) m = fmaxf(m, __shfl_xor(m, off, 64));
    float e = jv ? __expf(u - m) : 0.f;
    #pragma unroll
    for (int off = 1; off < 8; off <<= 1) e += __shfl_xor(e, off, 64);
    float fwd = m + __logf(e);
    if (j == 0) fsh[b] = fwd;

    // gold: thread handles batch tb, quarter q (64 steps each)
    int tb = tid & 63, q = tid >> 6;
    const int* tgp = tags + (size_t)tb * 512;
    float acc = 0.f;
    int tp = (q == 0) ? 5 : tgp[q * 64 - 1];
    for (int ss = q * 64; ss < q * 64 + 64; ++ss) {
        int tn = tgp[ss];
        acc += Tl[tn * 7 + tp] + feats[(size_t)(ss * 64 + tb) * 7 + tn];
        tp = tn;
    }
    if (q == 7) acc += Tl[42 + tgp[511]];
    red[tid] = acc;
    __syncthreads();
    if (tid < 64) {
        float g = red[tid];
        #pragma unroll
        for (int qq = 1; qq < 8; ++qq) g += red[tid + 64 * qq];
        red[tid] = fsh[tid] - g;
    }
    __syncthreads();
    if (tid < 64) {
        float v = red[tid];
        #pragma unroll
        for (int off = 1; off < 64; off <<= 1) v += __shfl_xor(v, off, 64);
        if (tid == 0) out[0] = v * (1.0f / 64.0f);
    }
}

// ---------------------------------------------------------------------------
extern "C" void kernel_launch(void* const* d_in, const int* in_sizes, int n_in,
                              void* d_out, int out_size, void* d_ws, size_t ws_size,
                              hipStream_t stream) {
    const int*   sent = (const int*)d_in[0];
    const int*   tags = (const int*)d_in[1];
    const float* h0   = (const float*)d_in[2];
    const float* c0   = (const float*)d_in[3];
    const float* emb  = (const float*)d_in[4];
    const float* wihf = (const float*)d_in[5];
    const float* whhf = (const float*)d_in[6];
    const float* bihf = (const float*)d_in[7];
    const float* bhhf = (const float*)d_in[8];
    const float* wihb = (const float*)d_in[9];
    const float* whhb = (const float*)d_in[10];
    const float* bihb = (const float*)d_in[11];
    const float* bhhb = (const float*)d_in[12];
    const float* wout = (const float*)d_in[13];
    const float* bout = (const float*)d_in[14];
    const float* trn  = (const float*)d_in[15];

    char* ws = (char*)d_ws;
    u16*   Xf     = (u16*)(ws);                       // 33,554,432 B
    u16*   Xb     = (u16*)(ws + 33554432);            // 33,554,432 B
    u16*   hfp    = (u16*)(ws + 67108864);            //  8,388,608 B
    u16*   hbp    = (u16*)(ws + 75497472);            //  8,388,608 B
    float* feats  = (float*)(ws + 83886080);          //    917,504 B
    float* chunkM = (float*)(ws + 84803584);          //    100,352 B

    k_inproj2<<<256, 512, 0, stream>>>(sent, emb, wihf, bihf, bhhf,
                                       wihb, bihb, bhhb, Xf, Xb);
    k_lstm<<<8, 512, 0, stream>>>(h0, c0, whhf, whhb, Xf, Xb, hfp, hbp);
    k_feats<<<1024, 256, 0, stream>>>(hfp, hbp, wout, bout, feats);
    k_crf_chunk<<<512, 64, 0, stream>>>(feats, trn, chunkM);
    k_crf_final<<<1, 512, 0, stream>>>(chunkM, trn, tags, feats, (float*)d_out);
}